// Round 1
// baseline (141.227 us; speedup 1.0000x reference)
//
#include <hip/hip_runtime.h>

// LinearMemoryBackend: y_t = M_t q_t, M_t = sum_{s<=t} v_s k_s^T
// Chunked-parallel formulation (chunk C=64):
//   S_c[e][d]   = sum_{t in c} k[t,e] v[t,d]                (kernel 1)
//   M_c         = exclusive prefix sum of S_c over chunks   (kernel 2, in-place)
//   y[t,d]      = sum_{s<=t, same chunk} (q_t . k_s) v[s,d] + sum_e q[t,e] M_c[e][d]   (kernel 3)
// ws usage: BH*NC*D*D floats = 16.78 MB (chunk-sum / prefix matrices).

#define B_   2
#define T_   4096
#define H_   8
#define D_   64
#define CH   64            // chunk length
#define NC   (T_ / CH)     // 64 chunks per (b,h)
#define BH   (B_ * H_)     // 16
#define SROW (H_ * D_)     // 512 floats between consecutive t
#define SB   (T_ * H_ * D_)

// ---------------- kernel 1: per-chunk outer-product sums ----------------
__global__ __launch_bounds__(256) void k_chunksum(const float* __restrict__ kp,
                                                  const float* __restrict__ vp,
                                                  float* __restrict__ W) {
  const int bid = blockIdx.x;
  const int c   = bid % NC;
  const int bh  = bid / NC;
  const int b   = bh / H_, h = bh % H_;
  const size_t base = (size_t)b * SB + (size_t)h * D_ + (size_t)(c * CH) * SROW;

  __shared__ float ks[CH][66];   // pad 66: reads ks[t][ty+16i] conflict-free
  __shared__ float vs[CH][65];   // pad 65: reads vs[t][4tx+j] 2-way (free)

  const int tid = threadIdx.x;
#pragma unroll
  for (int w = 0; w < 4; ++w) {
    const int f = tid + w * 256;       // 0..1023 float4 slots
    const int t = f >> 4;
    const int m = f & 15;
    const float4 k4 = *(const float4*)(kp + base + (size_t)t * SROW + m * 4);
    const float4 v4 = *(const float4*)(vp + base + (size_t)t * SROW + m * 4);
    ks[t][4*m+0] = k4.x; ks[t][4*m+1] = k4.y; ks[t][4*m+2] = k4.z; ks[t][4*m+3] = k4.w;
    vs[t][4*m+0] = v4.x; vs[t][4*m+1] = v4.y; vs[t][4*m+2] = v4.z; vs[t][4*m+3] = v4.w;
  }
  __syncthreads();

  const int tx = tid & 15, ty = tid >> 4;
  float acc[4][4];
#pragma unroll
  for (int i = 0; i < 4; ++i)
#pragma unroll
    for (int j = 0; j < 4; ++j) acc[i][j] = 0.f;

  for (int t = 0; t < CH; ++t) {
    float kr[4], vr[4];
#pragma unroll
    for (int i = 0; i < 4; ++i) kr[i] = ks[t][ty + 16 * i];
#pragma unroll
    for (int j = 0; j < 4; ++j) vr[j] = vs[t][4 * tx + j];
#pragma unroll
    for (int i = 0; i < 4; ++i)
#pragma unroll
      for (int j = 0; j < 4; ++j) acc[i][j] += kr[i] * vr[j];
  }

  // W[bid][e][d], e = k-index (row), d = v-index (col): W = S_c^T layout
  float* Wc = W + (size_t)bid * (D_ * D_);
#pragma unroll
  for (int i = 0; i < 4; ++i) {
    float4 st = make_float4(acc[i][0], acc[i][1], acc[i][2], acc[i][3]);
    *(float4*)(Wc + (ty + 16 * i) * D_ + 4 * tx) = st;
  }
}

// ---------------- kernel 2: exclusive prefix over chunks (in place) ----------------
__global__ __launch_bounds__(256) void k_prefix(float* __restrict__ W) {
  const int bh  = blockIdx.x >> 4;   // 16 segment-blocks per bh
  const int seg = blockIdx.x & 15;
  const int e   = seg * 256 + threadIdx.x;     // element 0..4095 of the D*D matrix
  float* base = W + (size_t)bh * NC * (D_ * D_) + e;
  float run = 0.f;
#pragma unroll 4
  for (int c = 0; c < NC; ++c) {
    const float s = base[(size_t)c * (D_ * D_)];
    base[(size_t)c * (D_ * D_)] = run;   // exclusive prefix
    run += s;
  }
}

// ---------------- kernel 3: intra-chunk causal part + inter-chunk part ----------------
__global__ __launch_bounds__(256) void k_output(const float* __restrict__ qp,
                                                const float* __restrict__ kp,
                                                const float* __restrict__ vp,
                                                const float* __restrict__ W,
                                                float* __restrict__ yp) {
  const int bid = blockIdx.x;
  const int c   = bid % NC;
  const int bh  = bid / NC;
  const int b   = bh / H_, h = bh % H_;
  const size_t base = (size_t)b * SB + (size_t)h * D_ + (size_t)(c * CH) * SROW;

  __shared__ float Qs[CH][66];   // Q tile (rows t), used in both phases
  __shared__ float Bs[CH][65];   // K tile -> V tile -> M^T tile (sequential reuse)
  __shared__ float Ps[CH][66];   // masked P = QK^T

  const int tid = threadIdx.x;

  // Prefetch everything from global up front (12+4 dwordx4 loads in flight).
  float4 q4[4], k4[4], v4[4], m4[4];
#pragma unroll
  for (int w = 0; w < 4; ++w) {
    const int f = tid + w * 256;
    const int t = f >> 4;
    const int m = f & 15;
    const size_t g = base + (size_t)t * SROW + m * 4;
    q4[w] = *(const float4*)(qp + g);
    k4[w] = *(const float4*)(kp + g);
    v4[w] = *(const float4*)(vp + g);
    m4[w] = *(const float4*)(W + (size_t)bid * (D_ * D_) + f * 4);
  }
#pragma unroll
  for (int w = 0; w < 4; ++w) {
    const int f = tid + w * 256;
    const int t = f >> 4;
    const int m = f & 15;
    Qs[t][4*m+0] = q4[w].x; Qs[t][4*m+1] = q4[w].y; Qs[t][4*m+2] = q4[w].z; Qs[t][4*m+3] = q4[w].w;
    Bs[t][4*m+0] = k4[w].x; Bs[t][4*m+1] = k4[w].y; Bs[t][4*m+2] = k4[w].z; Bs[t][4*m+3] = k4[w].w;
  }
  __syncthreads();

  const int tx = tid & 15, ty = tid >> 4;

  // Phase 1: P[t][s] = q_t . k_s ; thread tile t = ty+16i, s = 4tx+j
  float p[4][4];
#pragma unroll
  for (int i = 0; i < 4; ++i)
#pragma unroll
    for (int j = 0; j < 4; ++j) p[i][j] = 0.f;

  for (int e = 0; e < D_; ++e) {
    float qr[4], kr[4];
#pragma unroll
    for (int i = 0; i < 4; ++i) qr[i] = Qs[ty + 16 * i][e];
#pragma unroll
    for (int j = 0; j < 4; ++j) kr[j] = Bs[4 * tx + j][e];
#pragma unroll
    for (int i = 0; i < 4; ++i)
#pragma unroll
      for (int j = 0; j < 4; ++j) p[i][j] += qr[i] * kr[j];
  }
  // masked store of P (causal: s <= t)
#pragma unroll
  for (int i = 0; i < 4; ++i) {
    const int t = ty + 16 * i;
#pragma unroll
    for (int j = 0; j < 4; ++j) {
      const int s = 4 * tx + j;
      Ps[t][s] = (s <= t) ? p[i][j] : 0.f;
    }
  }
  __syncthreads();   // P visible; all K reads done -> Bs reusable

  // Bs := V tile
#pragma unroll
  for (int w = 0; w < 4; ++w) {
    const int f = tid + w * 256;
    const int t = f >> 4;
    const int m = f & 15;
    Bs[t][4*m+0] = v4[w].x; Bs[t][4*m+1] = v4[w].y; Bs[t][4*m+2] = v4[w].z; Bs[t][4*m+3] = v4[w].w;
  }
  __syncthreads();

  // Phase 2a: y += P V ; thread tile t = ty+16i, d = 4tx+j
  float acc[4][4];
#pragma unroll
  for (int i = 0; i < 4; ++i)
#pragma unroll
    for (int j = 0; j < 4; ++j) acc[i][j] = 0.f;

  for (int s = 0; s < CH; ++s) {
    float pr[4], vr[4];
#pragma unroll
    for (int i = 0; i < 4; ++i) pr[i] = Ps[ty + 16 * i][s];
#pragma unroll
    for (int j = 0; j < 4; ++j) vr[j] = Bs[s][4 * tx + j];
#pragma unroll
    for (int i = 0; i < 4; ++i)
#pragma unroll
      for (int j = 0; j < 4; ++j) acc[i][j] += pr[i] * vr[j];
  }
  __syncthreads();   // all V reads done -> Bs reusable

  // Bs := M^T tile (W layout is already [e][d])
#pragma unroll
  for (int w = 0; w < 4; ++w) {
    const int f = tid + w * 256;
    const int e = f >> 4;
    const int m = f & 15;
    Bs[e][4*m+0] = m4[w].x; Bs[e][4*m+1] = m4[w].y; Bs[e][4*m+2] = m4[w].z; Bs[e][4*m+3] = m4[w].w;
  }
  __syncthreads();

  // Phase 2b: y += Q M^T
  for (int e = 0; e < D_; ++e) {
    float qr[4], mr[4];
#pragma unroll
    for (int i = 0; i < 4; ++i) qr[i] = Qs[ty + 16 * i][e];
#pragma unroll
    for (int j = 0; j < 4; ++j) mr[j] = Bs[e][4 * tx + j];
#pragma unroll
    for (int i = 0; i < 4; ++i)
#pragma unroll
      for (int j = 0; j < 4; ++j) acc[i][j] += qr[i] * mr[j];
  }

  // Store y: contiguous float4 per thread-row
#pragma unroll
  for (int i = 0; i < 4; ++i) {
    float4 st = make_float4(acc[i][0], acc[i][1], acc[i][2], acc[i][3]);
    *(float4*)(yp + base + (size_t)(ty + 16 * i) * SROW + 4 * tx) = st;
  }
}

extern "C" void kernel_launch(void* const* d_in, const int* in_sizes, int n_in,
                              void* d_out, int out_size, void* d_ws, size_t ws_size,
                              hipStream_t stream) {
  const float* q = (const float*)d_in[0];
  const float* k = (const float*)d_in[1];
  const float* v = (const float*)d_in[2];
  float* y = (float*)d_out;
  float* W = (float*)d_ws;   // needs BH*NC*D*D*4 B = 16.78 MB of ws

  k_chunksum<<<BH * NC, 256, 0, stream>>>(k, v, W);
  k_prefix  <<<BH * 16, 256, 0, stream>>>(W);
  k_output  <<<BH * NC, 256, 0, stream>>>(q, k, v, W, y);
}

// Round 2
// 113.296 us; speedup vs baseline: 1.2465x; 1.2465x over previous
//
#include <hip/hip_runtime.h>

// LinearMemoryBackend: y_t = M_t q_t, M_t = sum_{s<=t} v_s k_s^T
// Chunked (C=64), MFMA bf16 version.
//  k1: W[bid][d][e] = S_c^T = sum_t v[t,d] k[t,e]   (K,V hi/lo bf16 split, fp32 out)
//  k2: exclusive prefix over chunks (fp32, float4)
//  k3: y = (QK^T masked)V + Q*M   (M hi/lo bf16 split)

#define B_   2
#define T_   4096
#define H_   8
#define D_   64
#define CH   64
#define NC   (T_ / CH)
#define BH   (B_ * H_)
#define SROW (H_ * D_)
#define SB   (T_ * H_ * D_)

typedef __attribute__((ext_vector_type(4))) float f32x4;
typedef __attribute__((ext_vector_type(8))) short bf16x8;

__device__ inline unsigned short f2bf(float f) {
  unsigned int u = __builtin_bit_cast(unsigned int, f);
  unsigned int r = (u + 0x7FFFu + ((u >> 16) & 1u)) >> 16;
  return (unsigned short)r;
}
__device__ inline float bf2f(unsigned short b) {
  unsigned int u = ((unsigned int)b) << 16;
  return __builtin_bit_cast(float, u);
}
__device__ inline void st4bf(unsigned short* p, float a, float b, float c, float d) {
  union { uint2 u; unsigned short s[4]; } x;
  x.s[0] = f2bf(a); x.s[1] = f2bf(b); x.s[2] = f2bf(c); x.s[3] = f2bf(d);
  *(uint2*)p = x.u;
}
__device__ inline bf16x8 ld128(const unsigned short* p) {
  union { uint4 u; bf16x8 v; } x;
  x.u = *(const uint4*)p;
  return x.v;
}

// fragment slot orderings (lane l: m = l&15, q = l>>4)
//  row-access operands (A rows / B^T rows loaded as 8 consecutive k): slot_A = m*4+q
//  transpose-staged operands (k = time contiguous):                   slot_V = (m&3)*16 + q*4 + (m>>2)

// ---------------- kernel 1: chunk outer-product sums via MFMA ----------------
__global__ __launch_bounds__(256) void k_chunksum(const float* __restrict__ kp,
                                                  const float* __restrict__ vp,
                                                  float* __restrict__ W) {
  const int bid = blockIdx.x;
  const int c   = bid % NC;
  const int bh  = bid / NC;
  const int b   = bh / H_, h = bh % H_;
  const size_t base = (size_t)b * SB + (size_t)h * D_ + (size_t)(c * CH) * SROW;

  __shared__ __align__(16) unsigned short KH[4096], KL[4096], VH[4096], VL[4096];

  const int tid = threadIdx.x;
  const int l = tid & 63, w = tid >> 6;
  const int mlan = l & 15, qlan = l >> 4;

  // stage K,V transposed (4x4 register transpose), hi/lo split
  {
    const int t0 = (tid >> 4) * 4;
    const int m0 = tid & 15;
    const int qs = (t0 >> 3) & 3, kbs = t0 >> 5, j0 = t0 & 4;
    float4 kr[4], vr[4];
#pragma unroll
    for (int i = 0; i < 4; ++i) {
      const size_t g = base + (size_t)(t0 + i) * SROW + 4 * m0;
      kr[i] = *(const float4*)(kp + g);
      vr[i] = *(const float4*)(vp + g);
    }
#pragma unroll
    for (int r = 0; r < 4; ++r) {
      const int d = 4 * m0 + r;
      const int slot = r * 16 + qs * 4 + (m0 & 3);
      const int addr = (((d >> 4) * 2 + kbs) * 64 + slot) * 8 + j0;
      float ke[4] = { ((const float*)&kr[0])[r], ((const float*)&kr[1])[r],
                      ((const float*)&kr[2])[r], ((const float*)&kr[3])[r] };
      float ve[4] = { ((const float*)&vr[0])[r], ((const float*)&vr[1])[r],
                      ((const float*)&vr[2])[r], ((const float*)&vr[3])[r] };
      float kh[4], vh[4];
#pragma unroll
      for (int i = 0; i < 4; ++i) { kh[i] = bf2f(f2bf(ke[i])); vh[i] = bf2f(f2bf(ve[i])); }
      st4bf(KH + addr, kh[0], kh[1], kh[2], kh[3]);
      st4bf(KL + addr, ke[0] - kh[0], ke[1] - kh[1], ke[2] - kh[2], ke[3] - kh[3]);
      st4bf(VH + addr, vh[0], vh[1], vh[2], vh[3]);
      st4bf(VL + addr, ve[0] - vh[0], ve[1] - vh[1], ve[2] - vh[2], ve[3] - vh[3]);
    }
  }
  __syncthreads();

  const int rslot = ((mlan & 3) << 4) + (qlan << 2) + (mlan >> 2);

  bf16x8 avh[2], avl[2];
#pragma unroll
  for (int kb = 0; kb < 2; ++kb) {
    avh[kb] = ld128(VH + ((w * 2 + kb) * 64 + rslot) * 8);
    avl[kb] = ld128(VL + ((w * 2 + kb) * 64 + rslot) * 8);
  }
  float* Wc = W + (size_t)bid * (D_ * D_);
#pragma unroll
  for (int te = 0; te < 4; ++te) {
    f32x4 acc = {0.f, 0.f, 0.f, 0.f};
#pragma unroll
    for (int kb = 0; kb < 2; ++kb) {
      bf16x8 bkh = ld128(KH + ((te * 2 + kb) * 64 + rslot) * 8);
      bf16x8 bkl = ld128(KL + ((te * 2 + kb) * 64 + rslot) * 8);
      acc = __builtin_amdgcn_mfma_f32_16x16x32_bf16(avh[kb], bkh, acc, 0, 0, 0);
      acc = __builtin_amdgcn_mfma_f32_16x16x32_bf16(avl[kb], bkh, acc, 0, 0, 0);
      acc = __builtin_amdgcn_mfma_f32_16x16x32_bf16(avh[kb], bkl, acc, 0, 0, 0);
    }
#pragma unroll
    for (int r = 0; r < 4; ++r)
      Wc[(16 * w + 4 * qlan + r) * D_ + 16 * te + mlan] = acc[r];
  }
}

// ---------------- kernel 2: exclusive prefix over chunks ----------------
__global__ __launch_bounds__(256) void k_prefix(float* __restrict__ W) {
  const int bh = blockIdx.x >> 2, part = blockIdx.x & 3;
  float* base = W + (size_t)bh * NC * (D_ * D_) + part * 1024 + threadIdx.x * 4;
  float rx = 0.f, ry = 0.f, rz = 0.f, rw = 0.f;
#pragma unroll 8
  for (int c = 0; c < NC; ++c) {
    float4* p = (float4*)(base + (size_t)c * (D_ * D_));
    float4 s = *p;
    float4 o; o.x = rx; o.y = ry; o.z = rz; o.w = rw;
    *p = o;
    rx += s.x; ry += s.y; rz += s.z; rw += s.w;
  }
}

// ---------------- kernel 3: y = (QK^T masked)V + Q*M via MFMA ----------------
__global__ __launch_bounds__(256) void k_output(const float* __restrict__ qp,
                                                const float* __restrict__ kp,
                                                const float* __restrict__ vp,
                                                const float* __restrict__ W,
                                                float* __restrict__ yp) {
  const int bid = blockIdx.x;
  const int c   = bid % NC;
  const int bh  = bid / NC;
  const int b   = bh / H_, h = bh % H_;
  const size_t base = (size_t)b * SB + (size_t)h * D_ + (size_t)(c * CH) * SROW;

  __shared__ __align__(16) unsigned short QF[4096], KF[4096], VF[4096],
                                          MH[4096], ML[4096], PS[64 * 72];

  const int tid = threadIdx.x;
  const int l = tid & 63, w = tid >> 6;
  const int mlan = l & 15, qlan = l >> 4;

  // --- stage Q, K (row-access A/B form) and M (hi/lo) ---
#pragma unroll
  for (int it = 0; it < 4; ++it) {
    const int f = tid + it * 256;
    const int t = f >> 4, m0 = f & 15;
    const int kb = m0 >> 3, q = (m0 & 7) >> 1, j0 = (m0 & 1) * 4;
    const int addr = (((t >> 4) * 2 + kb) * 64 + ((t & 15) * 4 + q)) * 8 + j0;
    const size_t g = base + (size_t)t * SROW + 4 * m0;
    float4 qv = *(const float4*)(qp + g);
    float4 kv = *(const float4*)(kp + g);
    st4bf(QF + addr, qv.x, qv.y, qv.z, qv.w);
    st4bf(KF + addr, kv.x, kv.y, kv.z, kv.w);
    float4 mv = *(const float4*)(W + (size_t)bid * (D_ * D_) + t * D_ + 4 * m0);
    float mh[4] = { bf2f(f2bf(mv.x)), bf2f(f2bf(mv.y)), bf2f(f2bf(mv.z)), bf2f(f2bf(mv.w)) };
    st4bf(MH + addr, mh[0], mh[1], mh[2], mh[3]);
    st4bf(ML + addr, mv.x - mh[0], mv.y - mh[1], mv.z - mh[2], mv.w - mh[3]);
  }
  // --- stage V transposed ---
  {
    const int s0 = (tid >> 4) * 4;
    const int m0 = tid & 15;
    const int qs = (s0 >> 3) & 3, kbs = s0 >> 5, j0 = s0 & 4;
    float4 vr[4];
#pragma unroll
    for (int i = 0; i < 4; ++i)
      vr[i] = *(const float4*)(vp + base + (size_t)(s0 + i) * SROW + 4 * m0);
#pragma unroll
    for (int r = 0; r < 4; ++r) {
      const int d = 4 * m0 + r;
      const int slot = r * 16 + qs * 4 + (m0 & 3);
      const int addr = (((d >> 4) * 2 + kbs) * 64 + slot) * 8 + j0;
      st4bf(VF + addr, ((const float*)&vr[0])[r], ((const float*)&vr[1])[r],
                       ((const float*)&vr[2])[r], ((const float*)&vr[3])[r]);
    }
  }
  __syncthreads();

  // --- Q A-frags ---
  bf16x8 aq[2];
#pragma unroll
  for (int kb = 0; kb < 2; ++kb)
    aq[kb] = ld128(QF + ((w * 2 + kb) * 64 + (mlan * 4 + qlan)) * 8);

  // --- matmul1: P = Q K^T (causal tiles only) ---
  f32x4 accP[4];
#pragma unroll
  for (int ts = 0; ts < 4; ++ts) accP[ts] = (f32x4){0.f, 0.f, 0.f, 0.f};
#pragma unroll
  for (int ts = 0; ts < 4; ++ts) {
    if (ts <= w) {
#pragma unroll
      for (int kb = 0; kb < 2; ++kb) {
        bf16x8 bk = ld128(KF + ((ts * 2 + kb) * 64 + (mlan * 4 + qlan)) * 8);
        accP[ts] = __builtin_amdgcn_mfma_f32_16x16x32_bf16(aq[kb], bk, accP[ts], 0, 0, 0);
      }
    }
  }
  // mask diagonal tile (keep s<=t)
#pragma unroll
  for (int ts = 0; ts < 4; ++ts) {
    if (ts == w) {
#pragma unroll
      for (int r = 0; r < 4; ++r)
        if (mlan > qlan * 4 + r) accP[ts][r] = 0.f;
    }
  }
  // write P strip (rows 16w..16w+15) to LDS row-major (stride 72)
#pragma unroll
  for (int ts = 0; ts < 4; ++ts)
#pragma unroll
    for (int r = 0; r < 4; ++r)
      PS[(16 * w + 4 * qlan + r) * 72 + 16 * ts + mlan] = f2bf(accP[ts][r]);

  // --- P A-frags (same-wave LDS round-trip; strip is wave-private) ---
  bf16x8 ap[2];
#pragma unroll
  for (int sb = 0; sb < 2; ++sb)
    ap[sb] = ld128(PS + (16 * w + mlan) * 72 + 32 * sb + 8 * qlan);

  const int rslot = ((mlan & 3) << 4) + (qlan << 2) + (mlan >> 2);

  f32x4 accY[4];
#pragma unroll
  for (int td = 0; td < 4; ++td) accY[td] = (f32x4){0.f, 0.f, 0.f, 0.f};

  // --- matmul2: Y += P V ---
#pragma unroll
  for (int td = 0; td < 4; ++td)
#pragma unroll
    for (int sb = 0; sb < 2; ++sb) {
      bf16x8 bv = ld128(VF + ((td * 2 + sb) * 64 + rslot) * 8);
      accY[td] = __builtin_amdgcn_mfma_f32_16x16x32_bf16(ap[sb], bv, accY[td], 0, 0, 0);
    }
  // --- matmul3: Y += Q * (Mhi + Mlo) ---
#pragma unroll
  for (int td = 0; td < 4; ++td)
#pragma unroll
    for (int kb = 0; kb < 2; ++kb) {
      bf16x8 bmh = ld128(MH + ((td * 2 + kb) * 64 + (mlan * 4 + qlan)) * 8);
      accY[td] = __builtin_amdgcn_mfma_f32_16x16x32_bf16(aq[kb], bmh, accY[td], 0, 0, 0);
      bf16x8 bml = ld128(ML + ((td * 2 + kb) * 64 + (mlan * 4 + qlan)) * 8);
      accY[td] = __builtin_amdgcn_mfma_f32_16x16x32_bf16(aq[kb], bml, accY[td], 0, 0, 0);
    }

  // --- store Y ---
#pragma unroll
  for (int td = 0; td < 4; ++td)
#pragma unroll
    for (int r = 0; r < 4; ++r)
      yp[base + (size_t)(16 * w + 4 * qlan + r) * SROW + 16 * td + mlan] = accY[td][r];
}

extern "C" void kernel_launch(void* const* d_in, const int* in_sizes, int n_in,
                              void* d_out, int out_size, void* d_ws, size_t ws_size,
                              hipStream_t stream) {
  const float* q = (const float*)d_in[0];
  const float* k = (const float*)d_in[1];
  const float* v = (const float*)d_in[2];
  float* y = (float*)d_out;
  float* W = (float*)d_ws;  // BH*NC*D*D*4 B = 16.78 MB

  k_chunksum<<<BH * NC, 256, 0, stream>>>(k, v, W);
  k_prefix  <<<BH * 4, 256, 0, stream>>>(W);
  k_output  <<<BH * NC, 256, 0, stream>>>(q, k, v, W, y);
}